// Round 6
// baseline (263.289 us; speedup 1.0000x reference)
//
#include <hip/hip_runtime.h>
#include <hip/hip_bf16.h>
#include <stdint.h>

// ---------------------------------------------------------------------------
// LocalAttentionBlock: B=2, L=2048, D=2048, H=16 (MQA, 1 KV head), hd=128,
// rope dims=64, window=512.
// R6: attention restructured with double-buffered K/V staging (prefetch tile
// t+1 before computing tile t; ONE barrier per tile, staging latency hidden
// behind MFMA/softmax) + mask-specialized softmax tiles. GEMMs unchanged.
// ---------------------------------------------------------------------------

typedef float  f32x4  __attribute__((ext_vector_type(4)));
typedef __bf16 bf16x8 __attribute__((ext_vector_type(8)));

#define ASYNC_LD16(gp, lp)                                                     \
  __builtin_amdgcn_global_load_lds(                                            \
      (__attribute__((address_space(1))) void*)(gp),                           \
      (__attribute__((address_space(3))) void*)(lp), 16, 0, 0)

// ---------------------------------------------------------------------------
// Fused prep: blocks [0,8192) convert x -> bf16; blocks [8192,16896) do the
// four weight transposes (fp32 [R][C] -> bf16 [C][R]).
// ---------------------------------------------------------------------------
__global__ __launch_bounds__(256) void prep_all(
    const float* __restrict__ x, __hip_bfloat16* __restrict__ xb,
    const float* __restrict__ Wq, const float* __restrict__ Wk,
    const float* __restrict__ Wv, const float* __restrict__ Wo,
    __hip_bfloat16* __restrict__ wqkvT, __hip_bfloat16* __restrict__ woT) {
  __shared__ float t[32][33];
  int bid = blockIdx.x;
  if (bid < 8192) {
    const int i = bid * 256 + threadIdx.x;
    const float4 v = ((const float4*)x)[i];
    __align__(8) __hip_bfloat16 o[4] = {
        __float2bfloat16(v.x), __float2bfloat16(v.y),
        __float2bfloat16(v.z), __float2bfloat16(v.w)};
    *(uint2*)(xb + (size_t)i * 4) = *(uint2*)o;
    return;
  }
  bid -= 8192;
  const float* src;
  __hip_bfloat16* dst;
  int C, cb, rb;
  if (bid < 4096) {
    src = Wq; dst = wqkvT; C = 2048; cb = bid & 63; rb = bid >> 6;
  } else if (bid < 4352) {
    const int l = bid - 4096;
    src = Wk; dst = wqkvT + 2048ull * 2048; C = 128; cb = l & 3; rb = l >> 2;
  } else if (bid < 4608) {
    const int l = bid - 4352;
    src = Wv; dst = wqkvT + 2176ull * 2048; C = 128; cb = l & 3; rb = l >> 2;
  } else {
    const int l = bid - 4608;
    src = Wo; dst = woT; C = 2048; cb = l & 63; rb = l >> 6;
  }
  const int c0 = cb * 32, r0 = rb * 32;
  const int xx = threadIdx.x & 31, y = threadIdx.x >> 5;
#pragma unroll
  for (int i = 0; i < 32; i += 8)
    t[y + i][xx] = src[(size_t)(r0 + y + i) * C + c0 + xx];
  __syncthreads();
#pragma unroll
  for (int i = 0; i < 32; i += 8)
    dst[(size_t)(c0 + y + i) * 2048 + r0 + xx] = __float2bfloat16(t[xx][y + i]);
}

// ---------------------------------------------------------------------------
// BK=64 GEMM core: acc[4][4] = A-tile x BT-tile^T. 128x128 tile, 4 waves in
// 2x2 of 64x64. LDS = two 32-k panels, XOR chunk swizzle (zero conflicts).
// ---------------------------------------------------------------------------
__device__ __forceinline__ void gemm_core64(const __bf16* __restrict__ A,
                                            const __bf16* __restrict__ BT,
                                            int K, __bf16* As, __bf16* Bs,
                                            f32x4 (&acc)[4][4]) {
  const int tid = threadIdx.x;
  const int wave = tid >> 6;
  const int lane = tid & 63;
  const int m0 = blockIdx.y * 128;
  const int n0 = blockIdx.x * 128;
  const int wm = (wave & 1) * 64;
  const int wn = (wave >> 1) * 64;
  const int ln = lane & 15;
  const int quad = lane >> 4;
  const int rdoff = (quad ^ ((ln >> 1) & 3)) * 8;

  size_t goff[4];
  int ldsoff[4];
#pragma unroll
  for (int i = 0; i < 4; i++) {
    const int cidx = (wave * 4 + i) * 64 + lane;
    const int p = cidx >> 9;
    const int pidx = cidx & 511;
    const int row = pidx >> 2;
    const int cc = pidx & 3;
    const int cg = cc ^ ((row >> 1) & 3);
    goff[i] = (size_t)row * K + p * 32 + cg * 8;
    ldsoff[i] = (wave * 4 + i) * 512;
  }
  const __bf16* Abase = A + (size_t)m0 * K;
  const __bf16* Bbase = BT + (size_t)n0 * K;

  for (int k0 = 0; k0 < K; k0 += 64) {
#pragma unroll
    for (int i = 0; i < 4; i++)
      ASYNC_LD16(Abase + k0 + goff[i], As + ldsoff[i]);
#pragma unroll
    for (int i = 0; i < 4; i++)
      ASYNC_LD16(Bbase + k0 + goff[i], Bs + ldsoff[i]);
    __syncthreads();
    bf16x8 af[4][2], bf[4][2];
#pragma unroll
    for (int i = 0; i < 4; i++)
#pragma unroll
      for (int p = 0; p < 2; p++)
        af[i][p] = *(const bf16x8*)&As[p * 4096 + (wm + i * 16 + ln) * 32 + rdoff];
#pragma unroll
    for (int j = 0; j < 4; j++)
#pragma unroll
      for (int p = 0; p < 2; p++)
        bf[j][p] = *(const bf16x8*)&Bs[p * 4096 + (wn + j * 16 + ln) * 32 + rdoff];
#pragma unroll
    for (int p = 0; p < 2; p++)
#pragma unroll
      for (int i = 0; i < 4; i++)
#pragma unroll
        for (int j = 0; j < 4; j++)
          acc[i][j] = __builtin_amdgcn_mfma_f32_16x16x32_bf16(af[i][p], bf[j][p],
                                                              acc[i][j], 0, 0, 0);
    __syncthreads();
  }
}

// ---------------------------------------------------------------------------
// QKV GEMM, fused epilogues. N=2304: n0<2048 -> q head (rope), n0==2048 -> k
// (rope), n0==2176 -> v written TRANSPOSED to vtd [b][128][2048].
// ---------------------------------------------------------------------------
__global__ __launch_bounds__(256) void gemm_qkv(
    const __bf16* __restrict__ A, const __bf16* __restrict__ BT,
    __hip_bfloat16* __restrict__ qd, __hip_bfloat16* __restrict__ kd,
    __hip_bfloat16* __restrict__ vtd, int K) {
  __shared__ __align__(16) __bf16 As[128 * 64];
  __shared__ __align__(16) __bf16 Bs[128 * 64];
  f32x4 acc[4][4];
  const f32x4 zero = {0.f, 0.f, 0.f, 0.f};
#pragma unroll
  for (int i = 0; i < 4; i++)
#pragma unroll
    for (int j = 0; j < 4; j++) acc[i][j] = zero;
  gemm_core64(A, BT, K, As, Bs, acc);

  const int tid = threadIdx.x;
  const int wave = tid >> 6;
  const int lane = tid & 63;
  const int quad = lane >> 4;
  const int ln = lane & 15;
  const int m0 = blockIdx.y * 128;
  const int n0 = blockIdx.x * 128;
  const int wm = (wave & 1) * 64;
  const int wn = (wave >> 1) * 64;

  if (n0 == 2176) {  // V: transposed write, no rope
    const int bb = m0 >> 11;
    const int mloc = m0 & 2047;
#pragma unroll
    for (int i = 0; i < 4; i++) {
      const int rb = mloc + wm + i * 16 + quad * 4;
#pragma unroll
      for (int j = 0; j < 4; j++) {
        const int col = wn + j * 16 + ln;
        __align__(8) __hip_bfloat16 t4[4];
#pragma unroll
        for (int r = 0; r < 4; r++) t4[r] = __float2bfloat16(acc[i][j][r]);
        *(uint2*)(vtd + ((size_t)(bb * 128 + col)) * 2048 + rb) = *(uint2*)t4;
      }
    }
    return;
  }

  __hip_bfloat16* dst;
  int dstride, dcol;
  if (n0 < 2048) {
    dst = qd; dstride = 2048; dcol = n0;
  } else {
    dst = kd; dstride = 128; dcol = 0;
  }
  const bool dorope = (wn == 0);
  float invf0 = 0.f, invf1 = 0.f;
  if (dorope) {
    invf0 = expf(-0.28782313662425574f * (float)ln);          // d = ln
    invf1 = expf(-0.28782313662425574f * (float)(16 + ln));   // d = 16+ln
  }

#pragma unroll
  for (int i = 0; i < 4; i++) {
#pragma unroll
    for (int r = 0; r < 4; r++) {
      const int row = m0 + wm + i * 16 + quad * 4 + r;
      float o0 = acc[i][0][r], o1 = acc[i][1][r];
      float o2 = acc[i][2][r], o3 = acc[i][3][r];
      if (dorope) {
        const float pos = (float)(row & 2047);
        float s0, c0, s1, c1;
        __sincosf(pos * invf0, &s0, &c0);
        __sincosf(pos * invf1, &s1, &c1);
        const float a0 = o0, b0 = o2, a1 = o1, b1 = o3;
        o0 = a0 * c0 - b0 * s0;
        o2 = a0 * s0 + b0 * c0;
        o1 = a1 * c1 - b1 * s1;
        o3 = a1 * s1 + b1 * c1;
      }
      __hip_bfloat16* rp = dst + (size_t)row * dstride + dcol + wn + ln;
      rp[0]  = __float2bfloat16(o0);
      rp[16] = __float2bfloat16(o1);
      rp[32] = __float2bfloat16(o2);
      rp[48] = __float2bfloat16(o3);
    }
  }
}

// ---------------------------------------------------------------------------
// Output GEMM: fp32 + bias epilogue.
// ---------------------------------------------------------------------------
__global__ __launch_bounds__(256) void gemm_out(
    const __bf16* __restrict__ A, const __bf16* __restrict__ BT,
    float* __restrict__ C, const float* __restrict__ bias, int N, int K) {
  __shared__ __align__(16) __bf16 As[128 * 64];
  __shared__ __align__(16) __bf16 Bs[128 * 64];
  f32x4 acc[4][4];
  const f32x4 zero = {0.f, 0.f, 0.f, 0.f};
#pragma unroll
  for (int i = 0; i < 4; i++)
#pragma unroll
    for (int j = 0; j < 4; j++) acc[i][j] = zero;
  gemm_core64(A, BT, K, As, Bs, acc);

  const int tid = threadIdx.x;
  const int wave = tid >> 6;
  const int lane = tid & 63;
  const int m0 = blockIdx.y * 128;
  const int n0 = blockIdx.x * 128;
  const int wm = (wave & 1) * 64;
  const int wn = (wave >> 1) * 64;
  const int lrow = lane & 15;
#pragma unroll
  for (int j = 0; j < 4; j++) {
    const int col = n0 + wn + j * 16 + lrow;
    const float bv = bias[col];
#pragma unroll
    for (int i = 0; i < 4; i++) {
#pragma unroll
      for (int r = 0; r < 4; r++) {
        const int row = m0 + wm + i * 16 + (lane >> 4) * 4 + r;
        C[(size_t)row * N + col] = acc[i][j][r] + bv;
      }
    }
  }
}

// ---------------------------------------------------------------------------
// Attention helpers.
// ---------------------------------------------------------------------------
__device__ __forceinline__ void stage_kv(const __bf16* __restrict__ kbase,
                                         const __bf16* __restrict__ vbase,
                                         int jt, __bf16* Kb, __bf16* Vb,
                                         int wave, int lane) {
  const int key4 = lane >> 2, uu = lane & 3;
  const int sw = (key4 >> 1) & 3;  // write-side swizzle: fetch chunk uu^sw
#pragma unroll
  for (int i = 0; i < 4; ++i) {
    const int c = wave * 4 + i;
    const int ks = c & 3, keybase = (c >> 2) * 16;
    ASYNC_LD16(kbase + (size_t)(jt + keybase + key4) * 128 + ks * 32 +
                   (uu ^ sw) * 8,
               Kb + ks * 2048 + keybase * 32);
  }
#pragma unroll
  for (int i = 0; i < 4; ++i) {
    const int c = wave * 4 + i;
    const int p = c & 1, dbase = (c >> 1) * 16;
    ASYNC_LD16(vbase + (size_t)(dbase + key4) * 2048 + jt + p * 32 +
                   (uu ^ sw) * 8,
               Vb + p * 4096 + dbase * 32);
  }
}

// MODE: 0 = no mask, 1 = window-low mask (t<=1), 2 = causal-high mask (t>=8)
template <int MODE>
__device__ __forceinline__ void attn_tile(
    const __bf16* __restrict__ Kb, const __bf16* __restrict__ Vb,
    __bf16* __restrict__ PsW, const bf16x8 (&qf)[2][4], f32x4 (&oacc)[2][8],
    float (&li)[2][4], int t, int wave, int quad, int ln, int rdoff) {
  const f32x4 zero = {0.f, 0.f, 0.f, 0.f};
  const float scale = 0.08838834764831845f;  // 1/sqrt(128)

  // S = Q K^T : 2 row groups x 4 col blocks x 4 k panels
  f32x4 sacc[2][4];
#pragma unroll
  for (int g = 0; g < 2; g++)
#pragma unroll
    for (int j = 0; j < 4; j++) sacc[g][j] = zero;
#pragma unroll
  for (int j = 0; j < 4; j++)
#pragma unroll
    for (int ks = 0; ks < 4; ks++) {
      const bf16x8 kf =
          *(const bf16x8*)&Kb[ks * 2048 + (j * 16 + ln) * 32 + rdoff];
#pragma unroll
      for (int g = 0; g < 2; g++)
        sacc[g][j] = __builtin_amdgcn_mfma_f32_16x16x32_bf16(qf[g][ks], kf,
                                                             sacc[g][j], 0, 0, 0);
    }

  // softmax (fixed max, clamp 60) + swizzled Ps store
#pragma unroll
  for (int g = 0; g < 2; g++)
#pragma unroll
    for (int j = 0; j < 4; j++) {
      const int ch = (j & 1) * 2 + (ln >> 3);
#pragma unroll
      for (int rp = 0; rp < 2; rp++) {
        const int swp = (quad * 2 + rp) & 3;
        __bf16* pw = PsW + (g * 2 + (j >> 1)) * 512 + (quad * 4 + rp * 2) * 32 +
                     (ch ^ swp) * 8 + (ln & 7);
#pragma unroll
        for (int r2 = 0; r2 < 2; r2++) {
          const int r = rp * 2 + r2;
          float vv = sacc[g][j][r] * scale;
          if (MODE == 1) {
            const int d0 = (wave * 32 + g * 16 + quad * 4 + r) - (j * 16 + ln);
            if (d0 >= (t << 6)) vv = -1e30f;
          } else if (MODE == 2) {
            const int d0 = (wave * 32 + g * 16 + quad * 4 + r) - (j * 16 + ln);
            if (d0 < ((t - 8) << 6)) vv = -1e30f;
          }
          vv = fminf(vv, 60.f);
          const float p = __expf(vv);
          li[g][r] += p;
          pw[r2 * 32] = (__bf16)p;
        }
      }
    }

  // O += P V
  const bf16x8 pf00 = *(const bf16x8*)&PsW[0 * 512 + ln * 32 + rdoff];
  const bf16x8 pf01 = *(const bf16x8*)&PsW[1 * 512 + ln * 32 + rdoff];
  const bf16x8 pf10 = *(const bf16x8*)&PsW[2 * 512 + ln * 32 + rdoff];
  const bf16x8 pf11 = *(const bf16x8*)&PsW[3 * 512 + ln * 32 + rdoff];
#pragma unroll
  for (int nb = 0; nb < 8; nb++) {
    const bf16x8 vf0 = *(const bf16x8*)&Vb[(nb * 16 + ln) * 32 + rdoff];
    const bf16x8 vf1 = *(const bf16x8*)&Vb[4096 + (nb * 16 + ln) * 32 + rdoff];
    oacc[0][nb] =
        __builtin_amdgcn_mfma_f32_16x16x32_bf16(pf00, vf0, oacc[0][nb], 0, 0, 0);
    oacc[0][nb] =
        __builtin_amdgcn_mfma_f32_16x16x32_bf16(pf01, vf1, oacc[0][nb], 0, 0, 0);
    oacc[1][nb] =
        __builtin_amdgcn_mfma_f32_16x16x32_bf16(pf10, vf0, oacc[1][nb], 0, 0, 0);
    oacc[1][nb] =
        __builtin_amdgcn_mfma_f32_16x16x32_bf16(pf11, vf1, oacc[1][nb], 0, 0, 0);
  }
}

// ---------------------------------------------------------------------------
// MFMA flash attention, 128-row Q tiles, double-buffered K/V staging:
// prefetch tile t+1 after the barrier, compute tile t, ONE barrier per tile
// (its vmcnt drain completes the prefetch; its sync protects buffer reuse).
// ---------------------------------------------------------------------------
__global__ __launch_bounds__(256) void attn_mfma(
    const __bf16* __restrict__ qb,   // [B*2048][2048]
    const __bf16* __restrict__ kb,   // [B*2048][128]
    const __bf16* __restrict__ vtb,  // [B][128][2048]
    __hip_bfloat16* __restrict__ o)  // [B*2048][2048]
{
  __shared__ __align__(16) __bf16 Ks[2][4 * 2048];  // 32 KB (double-buffered)
  __shared__ __align__(16) __bf16 Vs[2][2 * 4096];  // 32 KB (double-buffered)
  __shared__ __align__(16) __bf16 Ps[4][4 * 512];   // 16 KB (per-wave)
  const int tid = threadIdx.x;
  const int wave = tid >> 6;
  const int lane = tid & 63;
  const int quad = lane >> 4;
  const int ln = lane & 15;
  const int bid = blockIdx.x;
  const int q0 = (bid & 15) * 128;
  const int h = (bid >> 4) & 15;
  const int b = bid >> 8;
  const int rdoff = (quad ^ ((ln >> 1) & 3)) * 8;

  bf16x8 qf[2][4];
#pragma unroll
  for (int g = 0; g < 2; g++) {
    const __bf16* qrow =
        qb + ((size_t)(b * 2048 + q0 + wave * 32 + g * 16 + ln)) * 2048 + h * 128;
#pragma unroll
    for (int ks = 0; ks < 4; ks++)
      qf[g][ks] = *(const bf16x8*)(qrow + ks * 32 + quad * 8);
  }

  f32x4 oacc[2][8];
  const f32x4 zero = {0.f, 0.f, 0.f, 0.f};
#pragma unroll
  for (int g = 0; g < 2; g++)
#pragma unroll
    for (int nb = 0; nb < 8; nb++) oacc[g][nb] = zero;
  float li[2][4] = {{0.f, 0.f, 0.f, 0.f}, {0.f, 0.f, 0.f, 0.f}};

  const __bf16* kbase = kb + (size_t)b * 2048 * 128;
  const __bf16* vbase = vtb + (size_t)b * 128 * 2048;
  __bf16* PsW = Ps[wave];

  const int tstart = (q0 >= 512) ? 0 : (512 - q0) / 64;
  stage_kv(kbase, vbase, q0 - 512 + 64 * tstart, Ks[0], Vs[0], wave, lane);
  __syncthreads();  // drain initial stage

  for (int t = tstart; t < 10; ++t) {
    const int cur = (t - tstart) & 1;
    if (t + 1 < 10)
      stage_kv(kbase, vbase, q0 - 512 + 64 * (t + 1), Ks[cur ^ 1], Vs[cur ^ 1],
               wave, lane);
    if (t <= 1)
      attn_tile<1>(Ks[cur], Vs[cur], PsW, qf, oacc, li, t, wave, quad, ln, rdoff);
    else if (t >= 8)
      attn_tile<2>(Ks[cur], Vs[cur], PsW, qf, oacc, li, t, wave, quad, ln, rdoff);
    else
      attn_tile<0>(Ks[cur], Vs[cur], PsW, qf, oacc, li, t, wave, quad, ln, rdoff);
    __syncthreads();  // completes prefetch; protects cur for reuse at t+2
  }

#pragma unroll
  for (int off = 1; off < 16; off <<= 1)
#pragma unroll
    for (int g = 0; g < 2; g++)
#pragma unroll
      for (int r = 0; r < 4; r++) li[g][r] += __shfl_xor(li[g][r], off);

#pragma unroll
  for (int g = 0; g < 2; g++) {
    __hip_bfloat16* obase =
        o + ((size_t)(b * 2048 + q0 + wave * 32 + g * 16 + quad * 4)) * 2048 +
        h * 128 + ln;
#pragma unroll
    for (int r = 0; r < 4; r++) {
      const float inv = 1.0f / li[g][r];
#pragma unroll
      for (int nb = 0; nb < 8; nb++)
        obase[(size_t)r * 2048 + nb * 16] = __float2bfloat16(oacc[g][nb][r] * inv);
    }
  }
}

// ---------------------------------------------------------------------------
extern "C" void kernel_launch(void* const* d_in, const int* in_sizes, int n_in,
                              void* d_out, int out_size, void* d_ws,
                              size_t ws_size, hipStream_t stream) {
  const float* x = (const float*)d_in[0];
  const float* Wq = (const float*)d_in[1];
  const float* Wk = (const float*)d_in[2];
  const float* Wv = (const float*)d_in[3];
  const float* Wo = (const float*)d_in[4];
  const float* bo = (const float*)d_in[5];
  float* out = (float*)d_out;

  char* w = (char*)d_ws;
  auto alloc = [&](size_t bytes) {
    void* p = (void*)w;
    w += (bytes + 255) & ~(size_t)255;
    return p;
  };
  __bf16* xb = (__bf16*)alloc(4096ull * 2048 * 2);
  __hip_bfloat16* wqkvT = (__hip_bfloat16*)alloc(2304ull * 2048 * 2);
  __hip_bfloat16* woT = (__hip_bfloat16*)alloc(2048ull * 2048 * 2);
  __hip_bfloat16* qbuf = (__hip_bfloat16*)alloc(4096ull * 2048 * 2);
  __hip_bfloat16* kbuf = (__hip_bfloat16*)alloc(4096ull * 128 * 2);
  __hip_bfloat16* vtb = (__hip_bfloat16*)alloc(4096ull * 128 * 2);
  __hip_bfloat16* attnb = (__hip_bfloat16*)xb;  // alias: xb dead after gemm_qkv

  prep_all<<<16896, 256, 0, stream>>>(x, (__hip_bfloat16*)xb, Wq, Wk, Wv, Wo,
                                      wqkvT, woT);

  gemm_qkv<<<dim3(18, 32), 256, 0, stream>>>(xb, (const __bf16*)wqkvT, qbuf,
                                             kbuf, vtb, 2048);

  attn_mfma<<<512, 256, 0, stream>>>((const __bf16*)qbuf, (const __bf16*)kbuf,
                                     (const __bf16*)vtb, attnb);

  gemm_out<<<dim3(16, 32), 256, 0, stream>>>((const __bf16*)attnb,
                                             (const __bf16*)woT, out, bo, 2048,
                                             2048);
}